// Round 11
// baseline (718.188 us; speedup 1.0000x reference)
//
#include <hip/hip_runtime.h>

namespace {
constexpr int B = 2, H = 512, W = 512;
constexpr int KH = 32, KW = 32, K = 1024;
constexpr int HW = H * W;
constexpr int NBLOCKS = 1024;          // 4 blocks/CU at VGPR<=128 -> co-resident, 4 waves/SIMD
constexpr float YX_SCALE = 0.15625f;   // max(Kh/(0.4*H), Kw/(0.4*W)) == exactly 0.15625 in f32
constexpr float LAB_SCALE = 0.26f;
}

// ---------------------------------------------------------------------------
// Wave64 sum via DPP (HW-verified rounds 2/7/9). Full sum lands in lanes 48..63.
// ---------------------------------------------------------------------------
template <int CTRL>
__device__ __forceinline__ float dpp_add(float v) {
  int r = __builtin_amdgcn_update_dpp(0, __float_as_int(v), CTRL, 0xF, 0xF, true);
  return v + __int_as_float(r);
}
__device__ __forceinline__ float wave_sum64(float v) {
  v = dpp_add<0xB1>(v);    // quad_perm xor1
  v = dpp_add<0x4E>(v);    // quad_perm xor2
  v = dpp_add<0x141>(v);   // row_half_mirror
  v = dpp_add<0x140>(v);   // row_mirror
  v = dpp_add<0x142>(v);   // row_bcast15
  v = dpp_add<0x143>(v);   // row_bcast31
  return v;                // lanes 48..63 hold the 64-lane total
}

__device__ __forceinline__ float fast_rcp(float x) { return __builtin_amdgcn_rcpf(x); }

// Distributed gather of the 9 neighbor superpixels' {wsum, 5 feature sums}:
// lane<54 owns one (neighbor, component) pair and sums <=9 cell partials.
__device__ __forceinline__ float gather54(const float* __restrict__ pin,
                                          int b, int ki, int kj, int lane) {
  float g = 0.0f;
  const int n = lane / 6, comp = lane % 6;
  const int nki = ki + n / 3 - 1, nkj = kj + n % 3 - 1;
  if ((unsigned)nki < (unsigned)KH && (unsigned)nkj < (unsigned)KW) {
#pragma unroll
    for (int j = 0; j < 9; ++j) {
      const int ci = nki - (j / 3 - 1), cj = nkj - (j % 3 - 1);
      if ((unsigned)ci < (unsigned)KH && (unsigned)cj < (unsigned)KW)
        g += pin[(size_t)((b << 10) + (ci << 5) + cj) * 54 + j * 6 + comp];
    }
  }
  return g;
}

// ---------------------------------------------------------------------------
// Software grid barrier (HW-verified round 7): device-scope atomic + agent
// fences; one counter per sync point; bounded spin (fails loudly, never hangs).
// ---------------------------------------------------------------------------
__device__ __forceinline__ void grid_barrier(unsigned* __restrict__ ctr, int idx) {
  __syncthreads();
  if (threadIdx.x == 0) {
    __threadfence();                    // agent-scope release
    atomicAdd(&ctr[idx], 1u);
    unsigned spins = 0;
    while (__hip_atomic_load(&ctr[idx], __ATOMIC_ACQUIRE, __HIP_MEMORY_SCOPE_AGENT)
           < (unsigned)NBLOCKS) {
      __builtin_amdgcn_s_sleep(2);
      if (++spins > 2000000u) break;    // bail-out: wrong results, not a dead container
    }
    __threadfence();                    // agent-scope acquire
  }
  __syncthreads();
}

// Zero the 8 barrier counters (d_ws is re-poisoned to 0xAA before every launch).
__global__ void ssn_zero(unsigned* __restrict__ ctr) {
  if (threadIdx.x < 8) ctr[threadIdx.x] = 0u;
}

// ---------------------------------------------------------------------------
// Mega v2: init -> 4 fused assoc+update passes -> final in ONE launch.
// 1024 blocks x 256 threads; block = 2 cells, 2 waves/cell, 2 px/lane
// (the round-9-verified update2 mapping). LAB lives in 6 VGPRs across all
// phases. Phase bodies are the round-7/round-9 verified ones.
// ---------------------------------------------------------------------------
__global__ __launch_bounds__(256, 4) void ssn_mega2(
    const float* __restrict__ lab,
    float* __restrict__ outPFeat, float* __restrict__ outSpFeat,
    float* __restrict__ outAssoc, float* __restrict__ outIdx,
    float* __restrict__ pA, float* __restrict__ pB,
    unsigned* __restrict__ ctr) {
  __shared__ float sfg[2][54];        // gathered neighbor sums per cell
  __shared__ float comb[2][2][54];    // [sub-wave][cell-in-block][...]
  const int lane = threadIdx.x & 63;
  const int wid = threadIdx.x >> 6;
  const int cidx = wid >> 1, sub = wid & 1;
  const int c0 = blockIdx.x * 2;
  const int cell = c0 + cidx;          // this wave's cell
  const int b = cell >> 10;
  const int k = cell & (K - 1);
  const int ki = k >> 5, kj = k & 31;
  const float* labB = lab + (size_t)b * 3 * HW;

  // ---- phase 0: load LAB (2 px/lane), write pFeat, seed pA ----
  float l0[2], l1[2], l2[2];
  {
    float s0 = 0, s1 = 0, s2 = 0, s3 = 0, s4 = 0;
#pragma unroll
    for (int pxi = 0; pxi < 2; ++pxi) {
      const int t = lane + sub * 64 + pxi * 128;   // 0..255 unique per cell
      const int y = (ki << 4) + (t >> 4);
      const int x = (kj << 4) + (t & 15);
      const int pix = y * W + x;
      l0[pxi] = LAB_SCALE * labB[pix];
      l1[pxi] = LAB_SCALE * labB[HW + pix];
      l2[pxi] = LAB_SCALE * labB[2 * HW + pix];
      const float f0 = YX_SCALE * (float)y, f1 = YX_SCALE * (float)x;
      float* po = outPFeat + (size_t)b * 5 * HW + pix;
      po[0] = f0;
      po[HW] = f1;
      po[2 * HW] = l0[pxi];
      po[3 * HW] = l1[pxi];
      po[4 * HW] = l2[pxi];
      s0 += f0; s1 += f1; s2 += l0[pxi]; s3 += l1[pxi]; s4 += l2[pxi];
    }
    s0 = wave_sum64(s0); s1 = wave_sum64(s1); s2 = wave_sum64(s2);
    s3 = wave_sum64(s3); s4 = wave_sum64(s4);
    if (lane == 63) {
      comb[sub][cidx][0] = s0; comb[sub][cidx][1] = s1; comb[sub][cidx][2] = s2;
      comb[sub][cidx][3] = s3; comb[sub][cidx][4] = s4;
    }
  }
  __syncthreads();
  if (wid < 2 && lane < 54) {   // wave wid seeds cell c0+wid's 54 slots
    const int scell = c0 + wid;
    float v = 0.0f;
    if (lane == 24) v = 256.0f;
    else if (lane >= 25 && lane < 30)
      v = comb[0][wid][lane - 25] + comb[1][wid][lane - 25];
    pA[(size_t)scell * 54 + lane] = v;
  }
  grid_barrier(ctr, 0);

  // ---- phases 1..4: fused assoc + scatter-accumulate (update2 body) ----
  const float* cur = pA;
  float* nxt = pB;
#pragma unroll 1
  for (int it = 0; it < 4; ++it) {
    if (wid < 2 && lane < 54) {
      const int gcell = c0 + wid;
      const int gk = gcell & (K - 1);
      sfg[wid][lane] = gather54(cur, gcell >> 10, gk >> 5, gk & 31, lane);
    }
    __syncthreads();

    float sf[9][5];
    bool valid[9];
#pragma unroll
    for (int n = 0; n < 9; ++n) {
      const int ni = ki + n / 3 - 1, nj = kj + n % 3 - 1;
      valid[n] = ((unsigned)ni < (unsigned)KH) && ((unsigned)nj < (unsigned)KW);
      const float inv = fast_rcp(fmaxf(sfg[cidx][n * 6], 1e-10f));
#pragma unroll
      for (int c = 0; c < 5; ++c) sf[n][c] = sfg[cidx][n * 6 + 1 + c] * inv;
    }

    float acc[54];
#pragma unroll
    for (int i = 0; i < 54; ++i) acc[i] = 0.0f;

#pragma unroll
    for (int pxi = 0; pxi < 2; ++pxi) {
      const int t = lane + sub * 64 + pxi * 128;
      const int y = (ki << 4) + (t >> 4);
      const int x = (kj << 4) + (t & 15);
      float f[5];
      f[0] = YX_SCALE * (float)y;
      f[1] = YX_SCALE * (float)x;
      f[2] = l0[pxi]; f[3] = l1[pxi]; f[4] = l2[pxi];

      float d[9];
#pragma unroll
      for (int j = 0; j < 9; ++j) {
        float t0 = f[0] - sf[j][0];
        float dd = t0 * t0;
#pragma unroll
        for (int c = 1; c < 5; ++c) {
          const float tc = f[c] - sf[j][c];
          dd = fmaf(tc, tc, dd);
        }
        d[j] = dd;
      }
      float m = 1e30f;
#pragma unroll
      for (int j = 0; j < 9; ++j)
        if (valid[j]) m = fminf(m, d[j]);
      float e[9], sum = 0.0f;
#pragma unroll
      for (int j = 0; j < 9; ++j) {
        e[j] = valid[j] ? __expf(m - d[j]) : 0.0f;
        sum += e[j];
      }
      const float inv = fast_rcp(sum);
#pragma unroll
      for (int j = 0; j < 9; ++j) {
        const float w = e[j] * inv;
        acc[j * 6 + 0] += w;
#pragma unroll
        for (int c = 0; c < 5; ++c)
          acc[j * 6 + 1 + c] = fmaf(w, f[c], acc[j * 6 + 1 + c]);
      }
    }

#pragma unroll
    for (int i = 0; i < 54; ++i) acc[i] = wave_sum64(acc[i]);
    if (lane == 63) {
#pragma unroll
      for (int i = 0; i < 54; ++i) comb[sub][cidx][i] = acc[i];
    }
    __syncthreads();
    if (wid < 2 && lane < 54) {
      const int scell = c0 + wid;
      nxt[(size_t)scell * 54 + lane] = comb[0][wid][lane] + comb[1][wid][lane];
    }
    grid_barrier(ctr, 1 + it);
    const float* tmp = cur; cur = nxt; nxt = (float*)tmp;
  }

  // ---- phase 5: final assoc + outputs (final2 body, exact IEEE div) ----
  if (wid < 2 && lane < 54) {
    const int gcell = c0 + wid;
    const int gk = gcell & (K - 1);
    sfg[wid][lane] = gather54(cur, gcell >> 10, gk >> 5, gk & 31, lane);
  }
  __syncthreads();

  if (wid < 2 && lane < 5) {   // own-superpixel spFeat, layout (B,5,K)
    const int scell = c0 + wid;
    const int sb = scell >> 10, sk = scell & (K - 1);
    const float inv4 = 1.0f / fmaxf(sfg[wid][24], 1e-10f);
    outSpFeat[((size_t)sb * 5 + lane) * K + sk] = sfg[wid][25 + lane] * inv4;
  }

  float sf[9][5];
  bool valid[9];
#pragma unroll
  for (int n = 0; n < 9; ++n) {
    const int ni = ki + n / 3 - 1, nj = kj + n % 3 - 1;
    valid[n] = ((unsigned)ni < (unsigned)KH) && ((unsigned)nj < (unsigned)KW);
    const float inv = 1.0f / fmaxf(sfg[cidx][n * 6], 1e-10f);  // exact (output path)
#pragma unroll
    for (int c = 0; c < 5; ++c) sf[n][c] = sfg[cidx][n * 6 + 1 + c] * inv;
  }

#pragma unroll
  for (int pxi = 0; pxi < 2; ++pxi) {
    const int t = lane + sub * 64 + pxi * 128;
    const int y = (ki << 4) + (t >> 4);
    const int x = (kj << 4) + (t & 15);
    const int pix = y * W + x;
    float f[5];
    f[0] = YX_SCALE * (float)y;
    f[1] = YX_SCALE * (float)x;
    f[2] = l0[pxi]; f[3] = l1[pxi]; f[4] = l2[pxi];

    float d[9];
#pragma unroll
    for (int j = 0; j < 9; ++j) {
      float t0 = f[0] - sf[j][0];
      float dd = t0 * t0;
#pragma unroll
      for (int c = 1; c < 5; ++c) {
        const float tc = f[c] - sf[j][c];
        dd = fmaf(tc, tc, dd);
      }
      d[j] = dd;
    }
    float m = 1e30f;
#pragma unroll
    for (int j = 0; j < 9; ++j)
      if (valid[j]) m = fminf(m, d[j]);
    float e[9], sum = 0.0f;
#pragma unroll
    for (int j = 0; j < 9; ++j) {
      e[j] = valid[j] ? __expf(m - d[j]) : 0.0f;
      sum += e[j];
    }
    const float inv = 1.0f / sum;   // exact IEEE div on the direct output path

    float* oa = outAssoc + (size_t)b * 9 * HW + pix;
#pragma unroll
    for (int j = 0; j < 9; ++j) oa[(size_t)j * HW] = e[j] * inv;

    // argmax(prob) == first argmin(dist among valid); exp is monotone
    int bestj = 4;
    float bestd = 1e30f;
#pragma unroll
    for (int j = 0; j < 9; ++j)
      if (valid[j] && d[j] < bestd) { bestd = d[j]; bestj = j; }
    const int bi = ki + bestj / 3 - 1;
    const int bj = kj + bestj % 3 - 1;
    outIdx[(size_t)b * HW + pix] = (float)(bi * KW + bj);
  }
}

// ---------------------------------------------------------------------------
extern "C" void kernel_launch(void* const* d_in, const int* in_sizes, int n_in,
                              void* d_out, int out_size, void* d_ws, size_t ws_size,
                              hipStream_t stream) {
  const float* lab = (const float*)d_in[0];
  // d_in[1] (init_spIndx) is the deterministic regular grid; recomputed on device.

  float* out = (float*)d_out;
  float* outPFeat = out;                   // 2*5*512*512 = 2621440
  float* outSpFeat = outPFeat + 2621440;   // 2*5*1024    = 10240
  float* outAssoc = outSpFeat + 10240;     // 2*9*512*512 = 4718592
  float* outIdx = outAssoc + 4718592;      // 2*512*512   = 524288

  float* pA = (float*)d_ws;                // [B*K][9][6] = 442 KB
  float* pB = pA + (size_t)B * K * 54;     // ping-pong partner
  unsigned* ctr = (unsigned*)(pB + (size_t)B * K * 54);  // 8 barrier counters

  ssn_zero<<<1, 64, 0, stream>>>(ctr);
  ssn_mega2<<<NBLOCKS, 256, 0, stream>>>(lab, outPFeat, outSpFeat, outAssoc,
                                         outIdx, pA, pB, ctr);
}

// Round 12
// 128.358 us; speedup vs baseline: 5.5952x; 5.5952x over previous
//
#include <hip/hip_runtime.h>

namespace {
constexpr int B = 2, H = 512, W = 512;
constexpr int KH = 32, KW = 32, K = 1024;
constexpr int HW = H * W;
constexpr float YX_SCALE = 0.15625f;   // max(Kh/(0.4*H), Kw/(0.4*W)) == exactly 0.15625 in f32
constexpr float LAB_SCALE = 0.26f;
constexpr float INV256 = 1.0f / 256.0f;  // exact (pow2)
}

// ---------------------------------------------------------------------------
// Wave64 sum via DPP (HW-verified rounds 2/7/9/11). Sum lands in lanes 48..63.
// ---------------------------------------------------------------------------
template <int CTRL>
__device__ __forceinline__ float dpp_add(float v) {
  int r = __builtin_amdgcn_update_dpp(0, __float_as_int(v), CTRL, 0xF, 0xF, true);
  return v + __int_as_float(r);
}
__device__ __forceinline__ float wave_sum64(float v) {
  v = dpp_add<0xB1>(v);    // quad_perm xor1
  v = dpp_add<0x4E>(v);    // quad_perm xor2
  v = dpp_add<0x141>(v);   // row_half_mirror
  v = dpp_add<0x140>(v);   // row_mirror
  v = dpp_add<0x142>(v);   // row_bcast15
  v = dpp_add<0x143>(v);   // row_bcast31
  return v;                // lanes 48..63 hold the 64-lane total
}

__device__ __forceinline__ float fast_rcp(float x) { return __builtin_amdgcn_rcpf(x); }

// Distributed gather of the 9 neighbor superpixels' {wsum, 5 feature sums}:
// caller thread t<54 owns one (neighbor, component) pair, sums <=9 cell partials.
__device__ __forceinline__ float gather54(const float* __restrict__ pin,
                                          int b, int ki, int kj, int t) {
  float g = 0.0f;
  const int n = t / 6, comp = t % 6;
  const int nki = ki + n / 3 - 1, nkj = kj + n % 3 - 1;
  if ((unsigned)nki < (unsigned)KH && (unsigned)nkj < (unsigned)KW) {
#pragma unroll
    for (int j = 0; j < 9; ++j) {
      const int ci = nki - (j / 3 - 1), cj = nkj - (j % 3 - 1);
      if ((unsigned)ci < (unsigned)KH && (unsigned)cj < (unsigned)KW)
        g += pin[(size_t)((b << 10) + (ci << 5) + cj) * 54 + j * 6 + comp];
    }
  }
  return g;
}

// ---------------------------------------------------------------------------
// Fused init + update pass 1. 2048 blocks, 1 cell/block, 1 px/thread.
// Each block redundantly computes its 9 neighbor-cell MEANS (block-local:
// mean = sum * 1/256 exactly), writes the pFeat output for its own cell,
// then runs the assoc+accumulate body and writes partial1[cell][54].
// ---------------------------------------------------------------------------
__global__ __launch_bounds__(256) void ssn_initu1(const float* __restrict__ lab,
                                                  float* __restrict__ outPFeat,
                                                  float* __restrict__ pout) {
  __shared__ float nb[9][5];      // neighbor means
  __shared__ float comb[4][54];   // per-wave reduced contributions
  const int t = threadIdx.x;
  const int lane = t & 63;
  const int wid = t >> 6;
  const int cell = blockIdx.x;
  const int b = cell >> 10;
  const int k = cell & (K - 1);
  const int ki = k >> 5, kj = k & 31;
  const float* labB = lab + (size_t)b * 3 * HW;

  // ---- neighbor means: wave wid handles n = wid, wid+4 (+8 for wid 0) ----
#pragma unroll
  for (int rep = 0; rep < 3; ++rep) {
    const int n = wid + rep * 4;
    if (n > 8) break;
    const int ni = ki + n / 3 - 1, nj = kj + n % 3 - 1;
    const bool v = ((unsigned)ni < (unsigned)KH) && ((unsigned)nj < (unsigned)KW);
    float s0 = 0, s1 = 0, s2 = 0, s3 = 0, s4 = 0;
    if (v) {
#pragma unroll
      for (int px = 0; px < 4; ++px) {
        const int tt = lane + px * 64;
        const int y = (ni << 4) + (tt >> 4);
        const int x = (nj << 4) + (tt & 15);
        const int pix = y * W + x;
        const float a0 = LAB_SCALE * labB[pix];
        const float a1 = LAB_SCALE * labB[HW + pix];
        const float a2 = LAB_SCALE * labB[2 * HW + pix];
        const float f0 = YX_SCALE * (float)y, f1 = YX_SCALE * (float)x;
        if (n == 4) {  // own cell: emit pFeat while we have the values
          float* po = outPFeat + (size_t)b * 5 * HW + pix;
          po[0] = f0;
          po[HW] = f1;
          po[2 * HW] = a0;
          po[3 * HW] = a1;
          po[4 * HW] = a2;
        }
        s0 += f0; s1 += f1; s2 += a0; s3 += a1; s4 += a2;
      }
      s0 = wave_sum64(s0); s1 = wave_sum64(s1); s2 = wave_sum64(s2);
      s3 = wave_sum64(s3); s4 = wave_sum64(s4);
    }
    if (lane == 63) {
      nb[n][0] = s0 * INV256; nb[n][1] = s1 * INV256; nb[n][2] = s2 * INV256;
      nb[n][3] = s3 * INV256; nb[n][4] = s4 * INV256;
    }
  }
  __syncthreads();

  // ---- assoc + accumulate for own pixel (t = local pixel id) ----
  const int y = (ki << 4) + (t >> 4);
  const int x = (kj << 4) + (t & 15);
  const int pix = y * W + x;
  float f[5];
  f[0] = YX_SCALE * (float)y;
  f[1] = YX_SCALE * (float)x;
  f[2] = LAB_SCALE * labB[pix];
  f[3] = LAB_SCALE * labB[HW + pix];
  f[4] = LAB_SCALE * labB[2 * HW + pix];

  float d[9];
  bool valid[9];
#pragma unroll
  for (int j = 0; j < 9; ++j) {
    const int ni = ki + j / 3 - 1, nj = kj + j % 3 - 1;
    valid[j] = ((unsigned)ni < (unsigned)KH) && ((unsigned)nj < (unsigned)KW);
    float t0 = f[0] - nb[j][0];
    float dd = t0 * t0;
#pragma unroll
    for (int c = 1; c < 5; ++c) {
      const float tc = f[c] - nb[j][c];
      dd = fmaf(tc, tc, dd);
    }
    d[j] = dd;
  }
  float m = 1e30f;
#pragma unroll
  for (int j = 0; j < 9; ++j)
    if (valid[j]) m = fminf(m, d[j]);
  float e[9], sum = 0.0f;
#pragma unroll
  for (int j = 0; j < 9; ++j) {
    e[j] = valid[j] ? __expf(m - d[j]) : 0.0f;
    sum += e[j];
  }
  const float inv = fast_rcp(sum);

  // interleaved compute+reduce (keeps VGPR low: no acc[54] array)
#pragma unroll
  for (int n9 = 0; n9 < 9; ++n9) {
    const float w = e[n9] * inv;
    float r = wave_sum64(w);
    if (lane == 63) comb[wid][n9 * 6] = r;
#pragma unroll
    for (int c = 0; c < 5; ++c) {
      r = wave_sum64(w * f[c]);
      if (lane == 63) comb[wid][n9 * 6 + 1 + c] = r;
    }
  }
  __syncthreads();
  if (t < 54)
    pout[(size_t)cell * 54 + t] = comb[0][t] + comb[1][t] + comb[2][t] + comb[3][t];
}

// ---------------------------------------------------------------------------
// Update v3: 2048 blocks, 1 cell/block, 1 px/thread, 4 waves/cell.
// Interleaved DPP reduce -> ~90 VGPR -> 4 waves/SIMD (2x round-2 occupancy).
// ---------------------------------------------------------------------------
__global__ __launch_bounds__(256) void ssn_update3(const float* __restrict__ lab,
                                                   const float* __restrict__ pin,
                                                   float* __restrict__ pout) {
  __shared__ float sfg[54];
  __shared__ float comb[4][54];
  const int t = threadIdx.x;
  const int lane = t & 63;
  const int wid = t >> 6;
  const int cell = blockIdx.x;
  const int b = cell >> 10;
  const int k = cell & (K - 1);
  const int ki = k >> 5, kj = k & 31;

  if (t < 54) sfg[t] = gather54(pin, b, ki, kj, t);
  __syncthreads();

  float sf[9][5];
  bool valid[9];
#pragma unroll
  for (int n = 0; n < 9; ++n) {
    const int ni = ki + n / 3 - 1, nj = kj + n % 3 - 1;
    valid[n] = ((unsigned)ni < (unsigned)KH) && ((unsigned)nj < (unsigned)KW);
    const float inv = fast_rcp(fmaxf(sfg[n * 6], 1e-10f));
#pragma unroll
    for (int c = 0; c < 5; ++c) sf[n][c] = sfg[n * 6 + 1 + c] * inv;
  }

  const int y = (ki << 4) + (t >> 4);
  const int x = (kj << 4) + (t & 15);
  const int pix = y * W + x;
  const float* labB = lab + (size_t)b * 3 * HW;
  float f[5];
  f[0] = YX_SCALE * (float)y;
  f[1] = YX_SCALE * (float)x;
  f[2] = LAB_SCALE * labB[pix];
  f[3] = LAB_SCALE * labB[HW + pix];
  f[4] = LAB_SCALE * labB[2 * HW + pix];

  float d[9];
#pragma unroll
  for (int j = 0; j < 9; ++j) {
    float t0 = f[0] - sf[j][0];
    float dd = t0 * t0;
#pragma unroll
    for (int c = 1; c < 5; ++c) {
      const float tc = f[c] - sf[j][c];
      dd = fmaf(tc, tc, dd);
    }
    d[j] = dd;
  }
  float m = 1e30f;
#pragma unroll
  for (int j = 0; j < 9; ++j)
    if (valid[j]) m = fminf(m, d[j]);
  float e[9], sum = 0.0f;
#pragma unroll
  for (int j = 0; j < 9; ++j) {
    e[j] = valid[j] ? __expf(m - d[j]) : 0.0f;
    sum += e[j];
  }
  const float inv = fast_rcp(sum);

#pragma unroll
  for (int n9 = 0; n9 < 9; ++n9) {
    const float w = e[n9] * inv;
    float r = wave_sum64(w);
    if (lane == 63) comb[wid][n9 * 6] = r;
#pragma unroll
    for (int c = 0; c < 5; ++c) {
      r = wave_sum64(w * f[c]);
      if (lane == 63) comb[wid][n9 * 6 + 1 + c] = r;
    }
  }
  __syncthreads();
  if (t < 54)
    pout[(size_t)cell * 54 + t] = comb[0][t] + comb[1][t] + comb[2][t] + comb[3][t];
}

// ---------------------------------------------------------------------------
// Final (round-9 measured-passing body): 2048 blocks, 1 px/thread.
// Emits spFeat (B,5,K), psp_assoc (B,9,H,W), final_spIndx (as float).
// ---------------------------------------------------------------------------
__global__ __launch_bounds__(256) void ssn_final2(const float* __restrict__ lab,
                                                  const float* __restrict__ pin,
                                                  float* __restrict__ outSpFeat,
                                                  float* __restrict__ outAssoc,
                                                  float* __restrict__ outIdx) {
  __shared__ float sfg[54];
  const int tid = threadIdx.x;
  const int cell = blockIdx.x;
  const int b = cell >> 10;
  const int k = cell & (K - 1);
  const int ki = k >> 5, kj = k & 31;

  if (tid < 54) sfg[tid] = gather54(pin, b, ki, kj, tid);
  __syncthreads();

  if (tid < 5) {   // own-superpixel spFeat, layout (B,5,K)
    const float inv4 = 1.0f / fmaxf(sfg[24], 1e-10f);
    outSpFeat[((size_t)b * 5 + tid) * K + k] = sfg[25 + tid] * inv4;
  }

  float sf[9][5];
  bool valid[9];
#pragma unroll
  for (int n = 0; n < 9; ++n) {
    const int ni = ki + n / 3 - 1, nj = kj + n % 3 - 1;
    valid[n] = ((unsigned)ni < (unsigned)KH) && ((unsigned)nj < (unsigned)KW);
    const float inv = 1.0f / fmaxf(sfg[n * 6], 1e-10f);   // exact div (output path)
#pragma unroll
    for (int c = 0; c < 5; ++c) sf[n][c] = sfg[n * 6 + 1 + c] * inv;
  }

  const int y = (ki << 4) + (tid >> 4);
  const int x = (kj << 4) + (tid & 15);
  const int pix = y * W + x;
  const float* labB = lab + (size_t)b * 3 * HW;
  float f[5];
  f[0] = YX_SCALE * (float)y;
  f[1] = YX_SCALE * (float)x;
  f[2] = LAB_SCALE * labB[pix];
  f[3] = LAB_SCALE * labB[HW + pix];
  f[4] = LAB_SCALE * labB[2 * HW + pix];

  float d[9];
#pragma unroll
  for (int j = 0; j < 9; ++j) {
    float t0 = f[0] - sf[j][0];
    float dd = t0 * t0;
#pragma unroll
    for (int c = 1; c < 5; ++c) {
      const float tc = f[c] - sf[j][c];
      dd = fmaf(tc, tc, dd);
    }
    d[j] = dd;
  }
  float m = 1e30f;
#pragma unroll
  for (int j = 0; j < 9; ++j)
    if (valid[j]) m = fminf(m, d[j]);
  float e[9], sum = 0.0f;
#pragma unroll
  for (int j = 0; j < 9; ++j) {
    e[j] = valid[j] ? __expf(m - d[j]) : 0.0f;
    sum += e[j];
  }
  const float inv = 1.0f / sum;   // exact IEEE div on the direct output path

  float* oa = outAssoc + (size_t)b * 9 * HW + pix;
#pragma unroll
  for (int j = 0; j < 9; ++j) oa[(size_t)j * HW] = e[j] * inv;

  // argmax(prob) == first argmin(dist among valid); exp is monotone
  int bestj = 4;
  float bestd = 1e30f;
#pragma unroll
  for (int j = 0; j < 9; ++j)
    if (valid[j] && d[j] < bestd) { bestd = d[j]; bestj = j; }
  const int bi = ki + bestj / 3 - 1;
  const int bj = kj + bestj % 3 - 1;
  outIdx[(size_t)b * HW + pix] = (float)(bi * KW + bj);
}

// ---------------------------------------------------------------------------
extern "C" void kernel_launch(void* const* d_in, const int* in_sizes, int n_in,
                              void* d_out, int out_size, void* d_ws, size_t ws_size,
                              hipStream_t stream) {
  const float* lab = (const float*)d_in[0];
  // d_in[1] (init_spIndx) is the deterministic regular grid; recomputed on device.

  float* out = (float*)d_out;
  float* outPFeat = out;                   // 2*5*512*512 = 2621440
  float* outSpFeat = outPFeat + 2621440;   // 2*5*1024    = 10240
  float* outAssoc = outSpFeat + 10240;     // 2*9*512*512 = 4718592
  float* outIdx = outAssoc + 4718592;      // 2*512*512   = 524288

  float* pA = (float*)d_ws;                // [B*K][9][6] = 442 KB
  float* pB = pA + (size_t)B * K * 54;     // ping-pong partner

  ssn_initu1<<<B * K, 256, 0, stream>>>(lab, outPFeat, pA);       // init + pass 1
  ssn_update3<<<B * K, 256, 0, stream>>>(lab, pA, pB);            // pass 2
  ssn_update3<<<B * K, 256, 0, stream>>>(lab, pB, pA);            // pass 3
  ssn_update3<<<B * K, 256, 0, stream>>>(lab, pA, pB);            // pass 4
  ssn_final2<<<B * K, 256, 0, stream>>>(lab, pB, outSpFeat, outAssoc, outIdx);
}